// Round 3
// baseline (210.489 us; speedup 1.0000x reference)
//
#include <hip/hip_runtime.h>

#define B_  4096
#define G_  31
#define GG_ 961      // G*G
#define P_  8
#define C_  36       // P*(P+1)/2
#define R_  8        // b-values per block (block OWNS out[b0..b0+8) exclusively)
#define CH_ 4        // b-values per pipelined chunk (2 chunks of 4)
#define NT_ 4        // gh-tiles per wave (16 tiles x 64 lanes = 1024 >= 961)

// Native clang vector type: __builtin_nontemporal_load requires a vector of
// scalar types, not HIP's struct-wrapped float4.
typedef float floatx4 __attribute__((ext_vector_type(4)));

// Block covers ALL 961 gh cells x 8 b: each of 4 waves walks 4 gh-tiles.
// => outputs are block-exclusive: plain store, no zero-kernel, no atomics.
// Grid = 512 blocks = exactly 2 blocks/CU; ~200 VGPR fits 2 waves/SIMD.
// Param streamed nontemporally (zero reuse; keeps 135KB coef table L2-hot),
// double-buffered across tiles; coef prefetched one tile ahead.
// Quadratic form factorized: acc += pv[i] * sum_{j>=i} cf*pv[j] (44 FMA/b).
__global__ __launch_bounds__(256, 2)
void quadform_kernel(const float* __restrict__ param,
                     const float* __restrict__ coef,
                     float* __restrict__ out) {
    const int lane = threadIdx.x & 63;
    const int wv   = threadIdx.x >> 6;            // 4 waves/block
    const int b0   = blockIdx.x * R_;

    const floatx4* pb = reinterpret_cast<const floatx4*>(param);
    const size_t bstep = (size_t)GG_ * 2;         // float4 units per b

    // Per-tile addressing (t compile-time after unroll; wave wv owns tiles
    // {wv, wv+4, wv+8, wv+12} -> tile 15 is the 1-valid-lane tail).
    size_t base[NT_]; bool val[NT_]; int ghc[NT_];
    #pragma unroll
    for (int t = 0; t < NT_; ++t) {
        int gh = (t * 4 + wv) * 64 + lane;
        val[t]  = gh < GG_;
        ghc[t]  = val[t] ? gh : (GG_ - 1);        // clamp for safe addressing
        base[t] = ((size_t)b0 * GG_ + ghc[t]) * 2;
    }

    floatx4 qA[2][CH_][2];   // double-buffered chunk A (b0..b0+3)
    floatx4 qB[CH_][2];      // chunk B (b0+4..b0+7), single-buffered
    float   cfb[2][C_];      // double-buffered coeffs

#define LOADA(BUF, T)                                                          \
    {                                                                          \
        _Pragma("unroll")                                                      \
        for (int r = 0; r < CH_; ++r) {                                        \
            const floatx4* p_ = pb + base[T] + (size_t)r * bstep;              \
            qA[BUF][r][0] = __builtin_nontemporal_load(p_);                    \
            qA[BUF][r][1] = __builtin_nontemporal_load(p_ + 1);                \
        }                                                                      \
    }

#define LOADB(T)                                                               \
    {                                                                          \
        _Pragma("unroll")                                                      \
        for (int r = 0; r < CH_; ++r) {                                        \
            const floatx4* p_ = pb + base[T] + (size_t)(CH_ + r) * bstep;      \
            qB[r][0] = __builtin_nontemporal_load(p_);                         \
            qB[r][1] = __builtin_nontemporal_load(p_ + 1);                     \
        }                                                                      \
    }

#define LOADCF(BUF, T)                                                         \
    {                                                                          \
        const floatx4* cp = reinterpret_cast<const floatx4*>(coef)             \
                            + (size_t)ghc[T] * (C_ / 4);                       \
        _Pragma("unroll")                                                      \
        for (int q = 0; q < C_ / 4; ++q) {                                     \
            floatx4 v = cp[q];                                                 \
            cfb[BUF][4*q+0] = v.x; cfb[BUF][4*q+1] = v.y;                      \
            cfb[BUF][4*q+2] = v.z; cfb[BUF][4*q+3] = v.w;                      \
        }                                                                      \
        if (!val[T]) {                                                         \
            _Pragma("unroll")                                                  \
            for (int c = 0; c < C_; ++c) cfb[BUF][c] = 0.0f;                   \
        }                                                                      \
    }

    // acc = sum_i pv[i] * (sum_{j>=i} cf[c(i,j)] * pv[j]); c walks triu order.
#define DO_CHUNK(Q, CF, S0)                                                    \
    {                                                                          \
        _Pragma("unroll")                                                      \
        for (int r = 0; r < CH_; ++r) {                                        \
            const float pv[P_] = {Q[r][0].x, Q[r][0].y, Q[r][0].z, Q[r][0].w,  \
                                  Q[r][1].x, Q[r][1].y, Q[r][1].z, Q[r][1].w}; \
            float acc = 0.0f;                                                  \
            int c = 0;                                                         \
            _Pragma("unroll")                                                  \
            for (int i = 0; i < P_; ++i) {                                     \
                float tsum = 0.0f;                                             \
                _Pragma("unroll")                                              \
                for (int j = i; j < P_; ++j) {                                 \
                    tsum = fmaf(CF[c], pv[j], tsum); ++c;                      \
                }                                                              \
                acc = fmaf(pv[i], tsum, acc);                                  \
            }                                                                  \
            s[(S0) + r] += acc;                                                \
        }                                                                      \
    }

    float s[R_];
    #pragma unroll
    for (int r = 0; r < R_; ++r) s[r] = 0.0f;

    // Prologue: tile 0's coef + chunk A in flight before anything waits.
    LOADCF(0, 0);
    LOADA(0, 0);

    #pragma unroll
    for (int t = 0; t < NT_; ++t) {
        const int cur = t & 1, nxt = cur ^ 1;
        LOADB(t);                                  // chunk B of current tile
        if (t < NT_ - 1) LOADCF(nxt, t + 1);       // coef prefetch, next tile
        DO_CHUNK(qA[cur], cfb[cur], 0);            // compute b0..3 (covers qB)
        if (t < NT_ - 1) LOADA(nxt, t + 1);        // param prefetch, next tile
        DO_CHUNK(qB, cfb[cur], 4);                 // compute b4..7
    }

    // ---- interleaved butterflies: 8 independent shuffle chains ----
    #pragma unroll
    for (int off = 32; off; off >>= 1) {
        #pragma unroll
        for (int r = 0; r < R_; ++r) s[r] += __shfl_xor(s[r], off, 64);
    }

    // ---- combine the 4 waves in LDS, then 8 plain stores (block-exclusive) ----
    __shared__ float red[4][R_];
    if (lane == 0) {
        #pragma unroll
        for (int r = 0; r < R_; ++r) red[wv][r] = s[r];
    }
    __syncthreads();
    if (threadIdx.x < R_) {
        const int r = threadIdx.x;
        out[b0 + r] = red[0][r] + red[1][r] + red[2][r] + red[3][r];
    }
}

extern "C" void kernel_launch(void* const* d_in, const int* in_sizes, int n_in,
                              void* d_out, int out_size, void* d_ws, size_t ws_size,
                              hipStream_t stream) {
    const float* param = (const float*)d_in[0];   // [B, G, G, P] fp32
    const float* coef  = (const float*)d_in[1];   // [G, G, C]  fp32
    float* out = (float*)d_out;                   // [B] fp32

    // No zero kernel: every out[b] is written exactly once by its owning block.
    quadform_kernel<<<dim3(B_ / R_), 256, 0, stream>>>(param, coef, out);
}

// Round 4
// 176.107 us; speedup vs baseline: 1.1952x; 1.1952x over previous
//
#include <hip/hip_runtime.h>

#define B_  4096
#define G_  31
#define GG_ 961      // G*G
#define P_  8
#define C_  36       // P*(P+1)/2
#define R_  16       // b-values per block
#define CH_ 4        // b-values per pipelined chunk (4 chunks of 4)

// Native clang vector type: __builtin_nontemporal_load requires a vector of
// scalar types, not HIP's struct-wrapped float4.
typedef float floatx4 __attribute__((ext_vector_type(4)));

__global__ void zero_kernel(float* out, int n) {
    int i = blockIdx.x * blockDim.x + threadIdx.x;
    if (i < n) out[i] = 0.0f;
}

// Lane owns one gh cell (coeffs register-resident), block covers 256 gh x 16 b.
// Param is streamed nontemporally in four 4-b chunks, double-buffered so the
// next chunk's 8 dwordx4 loads are in flight while the current chunk computes.
// Quadratic form factorized: acc += pv[i] * sum_{j>=i} cf*pv[j]  (44 FMA/b vs 72).
// Per-wave butterfly reduce, then LDS combine across waves -> 16 atomics/block.
//
// NOTE (R3 post-mortem): do NOT trade block count for per-block work here.
// 512 long-lived blocks (8 waves/CU) collapsed MLP: 2.57 TB/s, VALUBusy 4.8%,
// latency-bound, +34 us. Short blocks x 1024 at 3 blocks/CU keep the bus full.
// Floor arithmetic: quadform window carries ~113 MB param reads PLUS ~78 MB of
// poison-fill LLC drain (measured R3) -> (113+78)/6.8 TB/s ~= 28 us. This
// kernel achieves ~27 us incl. zero+gaps => at the contaminated roofline.
__global__ __launch_bounds__(256, 3)
void quadform_kernel(const float* __restrict__ param,
                     const float* __restrict__ coef,
                     float* __restrict__ out) {
    const int lane    = threadIdx.x & 63;
    const int wv      = threadIdx.x >> 6;            // 4 waves/block
    const int gh_tile = blockIdx.x * 4 + wv;         // 0..15
    const int gh      = gh_tile * 64 + lane;         // 0..1023
    const bool valid  = gh < GG_;
    const int  ghc    = valid ? gh : (GG_ - 1);      // clamp for safe addressing

    const int b0 = blockIdx.y * R_;
    const floatx4* pb = reinterpret_cast<const floatx4*>(param);
    const size_t base  = ((size_t)b0 * GG_ + ghc) * 2;   // float4 units
    const size_t bstep = (size_t)GG_ * 2;

    floatx4 qA[CH_][2], qB[CH_][2];

    // Param loads: nontemporal (zero reuse) so the 135KB coef table stays L2-hot.
#define LOADC(Q, CHK)                                                          \
    {                                                                          \
        _Pragma("unroll")                                                      \
        for (int r = 0; r < CH_; ++r) {                                        \
            const floatx4* p_ = pb + base + (size_t)((CHK) * CH_ + r) * bstep; \
            Q[r][0] = __builtin_nontemporal_load(p_);                          \
            Q[r][1] = __builtin_nontemporal_load(p_ + 1);                      \
        }                                                                      \
    }

    // Issue the first two chunks before anything else (HBM latency ~900cy).
    LOADC(qA, 0);
    LOADC(qB, 1);

    // ---- per-lane coeffs (36 floats = 9 float4, 144B stride => 16B aligned) ----
    float cf[C_];
    {
        const floatx4* cp = reinterpret_cast<const floatx4*>(coef) + (size_t)ghc * (C_ / 4);
        #pragma unroll
        for (int q = 0; q < C_ / 4; ++q) {
            floatx4 v = cp[q];
            cf[4*q+0] = v.x; cf[4*q+1] = v.y; cf[4*q+2] = v.z; cf[4*q+3] = v.w;
        }
    }
    if (!valid) {
        #pragma unroll
        for (int c = 0; c < C_; ++c) cf[c] = 0.0f;   // tail lanes contribute 0
    }

    float s[R_];

    // acc = sum_i pv[i] * (sum_{j>=i} cf[c(i,j)] * pv[j]); c walks triu order.
#define DO_CHUNK(Q, S0)                                                        \
    {                                                                          \
        _Pragma("unroll")                                                      \
        for (int r = 0; r < CH_; ++r) {                                        \
            const float pv[P_] = {Q[r][0].x, Q[r][0].y, Q[r][0].z, Q[r][0].w,  \
                                  Q[r][1].x, Q[r][1].y, Q[r][1].z, Q[r][1].w}; \
            float acc = 0.0f;                                                  \
            int c = 0;                                                         \
            _Pragma("unroll")                                                  \
            for (int i = 0; i < P_; ++i) {                                     \
                float t = 0.0f;                                                \
                _Pragma("unroll")                                              \
                for (int j = i; j < P_; ++j) { t = fmaf(cf[c], pv[j], t); ++c; } \
                acc = fmaf(pv[i], t, acc);                                     \
            }                                                                  \
            s[(S0) + r] = acc;                                                 \
        }                                                                      \
    }

    // Software pipeline: next chunk's loads are outstanding during compute.
    DO_CHUNK(qA, 0);
    LOADC(qA, 2);
    DO_CHUNK(qB, 4);
    LOADC(qB, 3);
    DO_CHUNK(qA, 8);
    DO_CHUNK(qB, 12);

    // ---- interleaved butterflies: 16 independent shuffle chains ----
    #pragma unroll
    for (int off = 32; off; off >>= 1) {
        #pragma unroll
        for (int r = 0; r < R_; ++r) s[r] += __shfl_xor(s[r], off, 64);
    }

    // ---- combine the 4 waves in LDS, then 16 coalesced atomics per block ----
    __shared__ float red[4][R_];
    if (lane == 0) {
        #pragma unroll
        for (int r = 0; r < R_; ++r) red[wv][r] = s[r];
    }
    __syncthreads();
    if (threadIdx.x < R_) {
        const int r = threadIdx.x;
        float v = red[0][r] + red[1][r] + red[2][r] + red[3][r];
        atomicAdd(&out[b0 + r], v);
    }
}

extern "C" void kernel_launch(void* const* d_in, const int* in_sizes, int n_in,
                              void* d_out, int out_size, void* d_ws, size_t ws_size,
                              hipStream_t stream) {
    const float* param = (const float*)d_in[0];   // [B, G, G, P] fp32
    const float* coef  = (const float*)d_in[1];   // [G, G, C]  fp32
    float* out = (float*)d_out;                   // [B] fp32

    zero_kernel<<<(B_ + 255) / 256, 256, 0, stream>>>(out, B_);

    dim3 grid(4, B_ / R_);                        // 4 gh-groups x 256 b-tiles = 1024 blocks
    quadform_kernel<<<grid, 256, 0, stream>>>(param, coef, out);
}